// Round 1
// baseline (157.622 us; speedup 1.0000x reference)
//
#include <hip/hip_runtime.h>
#include <stdint.h>

#define NCHUNK 9
#define IN_DIM 128
#define OUT_DIM 128
#define NUM_F 8
#define CHUNK_ELEMS (OUT_DIM * IN_DIM)      // 16384 bf16 elems = 32 KB
#define W_ELEMS (NCHUNK * CHUNK_ELEMS)      // 147456 elems = 294912 B
#define B_TOTAL 131072

typedef __bf16 bf16x8 __attribute__((ext_vector_type(8)));
typedef float floatx16 __attribute__((ext_vector_type(16)));

typedef __attribute__((address_space(1))) const unsigned int gas_u32;
typedef __attribute__((address_space(3))) unsigned int las_u32;

// XOR-swizzled element offset (ushort units) within one 128x128 chunk.
// 16B groups (8 bf16) along i are permuted by o&7 so that the MFMA B-frag
// read (32 rows x 2 k-halves per wave instr) spreads uniformly over all 32
// LDS banks. Staging is a plain contiguous copy so swizzle survives
// global_load_lds's contiguous-lane constraint (m104).
__device__ __forceinline__ int wswz(int o, int i) {
  return o * IN_DIM + (((i >> 3) ^ (o & 7)) << 3) + (i & 7);
}

__device__ __forceinline__ unsigned short f2bf_rn(float f) {
  unsigned u = __builtin_bit_cast(unsigned, f);
  u += 0x7FFFu + ((u >> 16) & 1u);   // RTNE
  return (unsigned short)(u >> 16);
}

// ---------------- prep: fold coef/scale into bf16 weights + bias ----------
__global__ void skan_prep(const float* __restrict__ base_w,
                          const float* __restrict__ scale_sp,
                          const float* __restrict__ coef,
                          const float* __restrict__ conv_w,
                          const float* __restrict__ conv_b,
                          unsigned short* __restrict__ Wall,
                          float* __restrict__ bias) {
  int b = blockIdx.x;
  int i = threadIdx.x;                       // 0..127
  if (b < NCHUNK * OUT_DIM) {
    int c = b >> 7;                          // chunk 0..8
    int o = b & 127;
    float v;
    if (c == 0) {
      v = base_w[o * IN_DIM + i];
    } else {
      int f = c - 1;
      v = conv_w[(f * OUT_DIM + o) * IN_DIM + i] * coef[i * NUM_F + f] * scale_sp[o];
    }
    Wall[c * CHUNK_ELEMS + wswz(o, i)] = f2bf_rn(v);
  } else {
    float s = 0.f;
#pragma unroll
    for (int f = 0; f < NUM_F; ++f) s += conv_b[f * OUT_DIM + i];
    bias[i] = s * scale_sp[i];
  }
}

// ---------------- main ----------------
// round-to-nearest (half away from zero on magnitude): +0x8000 then take hi16.
// pack two results with one v_perm: result = hi16(lo) | hi16(hi)<<16
__device__ __forceinline__ unsigned pack2(float lo, float hi) {
  unsigned ulo = __builtin_bit_cast(unsigned, lo) + 0x8000u;
  unsigned uhi = __builtin_bit_cast(unsigned, hi) + 0x8000u;
  return __builtin_amdgcn_perm(uhi, ulo, 0x07060302u);
}

template<bool SILU>
__device__ __forceinline__ float act(float v, float gs) {
  if (SILU) {
    return v * __builtin_amdgcn_rcpf(1.f + __expf(-v));
  } else {
    return __sinf(v * gs);
  }
}

template<bool SILU>
__device__ __forceinline__ bf16x8 make_frag(float4 x0, float4 x1, float gs) {
  union { unsigned u[4]; bf16x8 v; } r;
  r.u[0] = pack2(act<SILU>(x0.x, gs), act<SILU>(x0.y, gs));
  r.u[1] = pack2(act<SILU>(x0.z, gs), act<SILU>(x0.w, gs));
  r.u[2] = pack2(act<SILU>(x1.x, gs), act<SILU>(x1.y, gs));
  r.u[3] = pack2(act<SILU>(x1.z, gs), act<SILU>(x1.w, gs));
  return r.v;
}

__device__ __forceinline__ void stage_chunk(const unsigned short* __restrict__ Wall,
                                            int c, unsigned short* dstbuf, int tid) {
  const char* src = (const char*)(Wall + c * CHUNK_ELEMS);
  char* dst = (char*)dstbuf;
  int off = tid * 16;
#pragma unroll
  for (int it = 0; it < 8; ++it) {          // 256 thr * 16B * 8 = 32 KB
    __builtin_amdgcn_global_load_lds((gas_u32*)(src + off), (las_u32*)(dst + off),
                                     16, 0, 0);
    off += 4096;
  }
}

__global__ __launch_bounds__(256, 2)
void skan_main(const float* __restrict__ x,
               const float* __restrict__ grid,
               const unsigned short* __restrict__ Wall,
               const float* __restrict__ bias,
               float* __restrict__ out) {
  __shared__ unsigned short sW[2][CHUNK_ELEMS];   // 2 x 32 KB double buffer

  const int tid  = threadIdx.x;
  const int lane = tid & 63;
  const int wv   = tid >> 6;        // wave 0..3
  const int m    = lane & 31;       // A row within wave tile / B row (=output col)
  const int q2   = lane >> 5;       // k-half selector
  const int rowBase = blockIdx.x * 128 + wv * 32;
  const int r = rowBase + m;

  // x slice owned by this lane: row r, cols s*16 + q2*8 + [0..8), s=0..7
  float4 xv0[8], xv1[8];
  {
    const float4* xrow = (const float4*)(x + (size_t)r * IN_DIM);
#pragma unroll
    for (int s = 0; s < 8; ++s) {
      xv0[s] = xrow[s * 4 + q2 * 2];
      xv1[s] = xrow[s * 4 + q2 * 2 + 1];
    }
  }

  floatx16 acc[4];
#pragma unroll
  for (int nt = 0; nt < 4; ++nt)
#pragma unroll
    for (int e = 0; e < 16; ++e) acc[nt][e] = 0.f;

  stage_chunk(Wall, 0, sW[0], tid);
  __syncthreads();

  const int m7 = m & 7;
  const int mrow = m * IN_DIM;      // ushort units

  // ---- chunk 0: silu / base weights ----
  {
    stage_chunk(Wall, 1, sW[1], tid);
    const unsigned short* Wb = sW[0];
#pragma unroll
    for (int s = 0; s < 8; ++s) {
      bf16x8 af = make_frag<true>(xv0[s], xv1[s], 0.f);
      int gp8 = (((s * 2 + q2) ^ m7) << 3);
#pragma unroll
      for (int nt = 0; nt < 4; ++nt) {
        bf16x8 bf = *(const bf16x8*)(Wb + nt * 32 * IN_DIM + mrow + gp8);
        acc[nt] = __builtin_amdgcn_mfma_f32_32x32x16_bf16(af, bf, acc[nt], 0, 0, 0);
      }
    }
    __syncthreads();
  }

  // ---- chunks 1..8: sin(grid[c-1] * x) ----
  for (int c = 1; c < NCHUNK; ++c) {
    if (c < NCHUNK - 1) stage_chunk(Wall, c + 1, sW[(c + 1) & 1], tid);
    const unsigned short* Wb = sW[c & 1];
    const float g = grid[c - 1];
#pragma unroll
    for (int s = 0; s < 8; ++s) {
      bf16x8 af = make_frag<false>(xv0[s], xv1[s], g);
      int gp8 = (((s * 2 + q2) ^ m7) << 3);
#pragma unroll
      for (int nt = 0; nt < 4; ++nt) {
        bf16x8 bf = *(const bf16x8*)(Wb + nt * 32 * IN_DIM + mrow + gp8);
        acc[nt] = __builtin_amdgcn_mfma_f32_32x32x16_bf16(af, bf, acc[nt], 0, 0, 0);
      }
    }
    __syncthreads();
  }

  // ---- epilogue: C/D layout col=lane&31, row=(e&3)+8*(e>>2)+4*q2 (m74/m101) ----
  float* orow = out + (size_t)rowBase * OUT_DIM;
#pragma unroll
  for (int nt = 0; nt < 4; ++nt) {
    float bv = bias[nt * 32 + m];
#pragma unroll
    for (int e = 0; e < 16; ++e) {
      int rl = (e & 3) + 8 * (e >> 2) + 4 * q2;
      orow[(size_t)rl * OUT_DIM + nt * 32 + m] = acc[nt][e] + bv;
    }
  }
}

extern "C" void kernel_launch(void* const* d_in, const int* in_sizes, int n_in,
                              void* d_out, int out_size, void* d_ws, size_t ws_size,
                              hipStream_t stream) {
  const float* x      = (const float*)d_in[0];
  const float* grid   = (const float*)d_in[1];
  const float* base_w = (const float*)d_in[2];
  const float* scale  = (const float*)d_in[3];
  const float* coef   = (const float*)d_in[4];
  const float* conv_w = (const float*)d_in[5];
  const float* conv_b = (const float*)d_in[6];

  unsigned short* Wall = (unsigned short*)d_ws;
  float* bias = (float*)((char*)d_ws + (size_t)W_ELEMS * 2);
  float* out  = (float*)d_out;

  // prep must run every launch: d_ws is re-poisoned before each timed call
  skan_prep<<<NCHUNK * OUT_DIM + 1, 128, 0, stream>>>(base_w, scale, coef,
                                                      conv_w, conv_b, Wall, bias);
  skan_main<<<B_TOTAL / 128, 256, 0, stream>>>(x, grid, Wall, bias, out);
}